// Round 4
// baseline (262.956 us; speedup 1.0000x reference)
//
#include <hip/hip_runtime.h>
#include <hip/hip_bf16.h>
#include <cmath>

#define NB 4
#define NM 32
#define DKc 256
#define DVc 32
#define NP 4096

using bf16x8 = __attribute__((ext_vector_type(8))) short;
using f32x4  = __attribute__((ext_vector_type(4))) float;

__device__ __forceinline__ unsigned short f2bf(float f) {
    union { float f; unsigned u; } x; x.f = f;
    unsigned r = 0x7FFFu + ((x.u >> 16) & 1u);
    return (unsigned short)((x.u + r) >> 16);
}

// ---------------- k_prep: fc transpose (1024 blocks) + W transposes (32) + vproj (64) ----------------
__global__ __launch_bounds__(256) void k_prep(
    const float* __restrict__ fc, unsigned short* __restrict__ fcT,
    const float* __restrict__ Q, unsigned short* __restrict__ WTq,
    const float* __restrict__ K, unsigned short* __restrict__ WTk,
    const float* __restrict__ fm, const float* __restrict__ V, float* __restrict__ vproj) {
    int x = blockIdx.x;
    int t = threadIdx.x;
    if (x < 1056) {
        __shared__ float tile[64][65];
        const float* s; unsigned short* d; int R, C, r0, c0;
        if (x < 1024) {
            int bb = x >> 8, rest = x & 255;
            R = 256; C = 4096;
            r0 = (rest >> 6) * 64; c0 = (rest & 63) * 64;
            s = fc + (long)bb * 256 * 4096; d = fcT + (long)bb * 256 * 4096;
        } else {
            int i = x - 1024;
            int mat = i >> 4, idx = i & 15;
            R = 256; C = 256;
            r0 = (idx >> 2) * 64; c0 = (idx & 3) * 64;
            s = mat ? K : Q; d = mat ? WTk : WTq;
        }
        #pragma unroll
        for (int j = 0; j < 16; ++j) {
            int i = t + 256 * j;
            int r = i >> 6, c = i & 63;
            tile[r][c] = s[(long)(r0 + r) * C + c0 + c];
        }
        __syncthreads();
        #pragma unroll
        for (int j = 0; j < 8; ++j) {
            int i = t + 256 * j;
            int row = i >> 5;
            int pr = i & 31;
            float f0 = tile[2 * pr][row];
            float f1 = tile[2 * pr + 1][row];
            unsigned pack = (unsigned)f2bf(f0) | ((unsigned)f2bf(f1) << 16);
            reinterpret_cast<unsigned*>(d)[(((long)(c0 + row) * R + r0) >> 1) + pr] = pack;
        }
    } else {
        __shared__ float Vl[32][32];
        __shared__ float fml[32][256];
        int i = x - 1056;
        int b = i >> 4, p0 = (i & 15) * 256;
        #pragma unroll
        for (int j = 0; j < 4; ++j) { int ii = t + 256 * j; Vl[ii >> 5][ii & 31] = V[ii]; }
        for (int j = 0; j < 32; ++j) {
            int ii = t + 256 * j;
            int dd = ii >> 8, c = ii & 255;
            fml[dd][c] = fm[((long)b * DVc + dd) * NP + p0 + c];
        }
        __syncthreads();
        float acc[32];
        #pragma unroll
        for (int e = 0; e < 32; ++e) acc[e] = 0.f;
        for (int dd = 0; dd < 32; ++dd) {
            float fv = fml[dd][t];
            #pragma unroll
            for (int e = 0; e < 32; ++e) acc[e] += fv * Vl[dd][e];
        }
        #pragma unroll
        for (int e = 0; e < 32; ++e) vproj[((long)b * DVc + e) * NP + p0 + t] = acc[e];
    }
}

// ---------------- k_proj: full-e (256) per 64-p tile. grid (64, 8=b*mat) ----------------
// both outputs fp32 [b][e][p]: mat==0 -> qproj, mat==1 -> kproj
__global__ __launch_bounds__(256) void k_proj(
    const unsigned short* __restrict__ WTq, const unsigned short* __restrict__ WTk,
    const unsigned short* __restrict__ fcT,
    float* __restrict__ qproj, float* __restrict__ kproj) {
    int t = threadIdx.x;
    int wave = t >> 6, lane = t & 63;
    int y = blockIdx.y;
    int b = y & 3, mat = y >> 2;
    int p0 = blockIdx.x * 64;
    int ln = lane & 15, quad = lane >> 4;
    const unsigned short* WT = mat ? WTk : WTq;
    float* dst = mat ? kproj : qproj;
    int e0w = wave * 64;
    const unsigned short* bbase = fcT + ((long)b * NP + p0 + ln) * DKc + quad * 8;
    f32x4 acc[4][4] = {};
    for (int kk = 0; kk < DKc; kk += 32) {
        bf16x8 a[4], bb[4];
        #pragma unroll
        for (int i = 0; i < 4; ++i)
            a[i] = *reinterpret_cast<const bf16x8*>(WT + (long)(e0w + i * 16 + ln) * DKc + quad * 8 + kk);
        #pragma unroll
        for (int j = 0; j < 4; ++j)
            bb[j] = *reinterpret_cast<const bf16x8*>(bbase + (long)j * 16 * DKc + kk);
        #pragma unroll
        for (int i = 0; i < 4; ++i)
            #pragma unroll
            for (int j = 0; j < 4; ++j)
                acc[i][j] = __builtin_amdgcn_mfma_f32_16x16x32_bf16(a[i], bb[j], acc[i][j], 0, 0, 0);
    }
    #pragma unroll
    for (int i = 0; i < 4; ++i)
        #pragma unroll
        for (int j = 0; j < 4; ++j)
            #pragma unroll
            for (int r = 0; r < 4; ++r) {
                int e = e0w + i * 16 + quad * 4 + r, p = p0 + j * 16 + ln;
                dst[((long)b * DKc + e) * NP + p] = acc[i][j][r];
            }
}

// ---------------- k_fused: scores + softmax(w) + ctx + epilogue ----------------
// grid 256: blockIdx.x = b*64 + hrow (b-blocks of an hrow land on same XCD: stride 64 % 8 == 0).
// 1024 threads = 16 waves. Phase A: lane = (egw<<4)|wq; thread owns e0=wave*16+egw*4 (4 e) x w0=wq*4 (4 w).
__global__ __launch_bounds__(1024, 4) void k_fused(
    const float* __restrict__ qproj, const float* __restrict__ kproj,
    const float* __restrict__ kbuf, const float* __restrict__ vproj,
    const float* __restrict__ vbuf, const float* __restrict__ fm,
    float* __restrict__ out, float scale) {
    __shared__ float red[16 * 1099];   // wave-stride 1099 (odd): 16-wave column reads conflict-free
    __shared__ float sc[32][68];
    int t = threadIdx.x;
    int b = blockIdx.x >> 6, hrow = blockIdx.x & 63;
    int p0h = hrow * 64;
    int wave = t >> 6, lane = t & 63;
    int wq = lane & 15, egw = lane >> 4;
    int e0 = wave * 16 + egw * 4;
    int w0 = wq * 4;

    // q fragment: qv[j] = qproj[b][e0+j][p0h+w0 .. +3]
    f32x4 qv[4];
    const float* qp = qproj + ((long)b * DKc + e0) * NP + p0h + w0;
    #pragma unroll
    for (int j = 0; j < 4; ++j) qv[j] = *reinterpret_cast<const f32x4*>(qp + (long)j * NP);

    #pragma unroll
    for (int mc = 0; mc < 2; ++mc) {
        f32x4 acc[16];
        #pragma unroll
        for (int mi = 0; mi < 16; ++mi) acc[mi] = (f32x4){0.f, 0.f, 0.f, 0.f};
        #pragma unroll
        for (int mi = 0; mi < 16; ++mi) {
            int m = mc * 16 + mi;
            const float* kp = (m < 4 ? kproj + (long)m * DKc * NP : kbuf + (long)(m - 4) * DKc * NP)
                              + (long)e0 * NP + p0h + w0;
            #pragma unroll
            for (int j = 0; j < 4; ++j) {
                f32x4 kv = *reinterpret_cast<const f32x4*>(kp + (long)j * NP);
                acc[mi] += qv[j] * kv;
            }
        }
        // combine the 4 egw groups within each wave (lane^16, lane^32)
        #pragma unroll
        for (int mi = 0; mi < 16; ++mi)
            #pragma unroll
            for (int c = 0; c < 4; ++c) {
                float v = acc[mi][c];
                v += __shfl_xor(v, 16);
                v += __shfl_xor(v, 32);
                acc[mi][c] = v;
            }
        if (lane < 16) {
            #pragma unroll
            for (int mi = 0; mi < 16; ++mi)
                *reinterpret_cast<f32x4*>(&red[wave * 1099 + mi * 69 + lane * 4]) = acc[mi];
        }
        __syncthreads();
        {   // cross-wave reduce: thread (mr=t>>6, w=t&63) sums 16 wave partials
            int mr = t >> 6, w = t & 63;
            float s = 0.f;
            #pragma unroll
            for (int v = 0; v < 16; ++v) s += red[v * 1099 + mr * 69 + w];
            sc[mc * 16 + mr][w] = s * scale;
        }
        __syncthreads();
    }
    // softmax over w: wave handles rows 2*wave, 2*wave+1
    #pragma unroll
    for (int r = 0; r < 2; ++r) {
        int m = wave * 2 + r;
        float x = sc[m][lane];
        float mx = x;
        #pragma unroll
        for (int d = 1; d < 64; d <<= 1) mx = fmaxf(mx, __shfl_xor(mx, d));
        float e = __expf(x - mx);
        float sum = e;
        #pragma unroll
        for (int d = 1; d < 64; d <<= 1) sum += __shfl_xor(sum, d);
        sc[m][lane] = e / sum;
    }
    __syncthreads();
    // ctx + epilogue: dg = t>>6 (16 groups x 2 d), w = t&63
    {
        int dg = t >> 6, w = t & 63;
        float c0 = 0.f, c1 = 0.f;
        #pragma unroll
        for (int m = 0; m < NM; ++m) {
            float a = sc[m][w];
            const float* vp = (m < 4 ? vproj + (long)m * DVc * NP : vbuf + (long)(m - 4) * DVc * NP)
                              + (long)(dg * 2) * NP + p0h + w;
            c0 += a * vp[0];
            c1 += a * vp[NP];
        }
        long gi0 = ((long)b * DVc + dg * 2) * NP + p0h + w;
        long gi1 = gi0 + NP;
        out[gi0] = fm[gi0] + 0.5f * c0;
        out[gi1] = fm[gi1] + 0.5f * c1;
    }
}

extern "C" void kernel_launch(void* const* d_in, const int* in_sizes, int n_in,
                              void* d_out, int out_size, void* d_ws, size_t ws_size,
                              hipStream_t stream) {
    const float* fc = (const float*)d_in[0];
    const float* fm = (const float*)d_in[1];
    const float* kb = (const float*)d_in[2];
    const float* vb = (const float*)d_in[3];
    const float* Q  = (const float*)d_in[4];
    const float* K  = (const float*)d_in[5];
    const float* V  = (const float*)d_in[6];
    float* out = (float*)d_out;
    char* ws = (char*)d_ws;
    unsigned short* fcT   = (unsigned short*)(ws);                 // 8388608 B
    unsigned short* WTq   = (unsigned short*)(ws + 8388608);       // 131072 B
    unsigned short* WTk   = (unsigned short*)(ws + 8519680);       // 131072 B
    float*          qproj = (float*)(ws + 8650752);                // 16777216 B
    float*          kproj = (float*)(ws + 25427968);               // 16777216 B
    float*          vproj = (float*)(ws + 42205184);               // 2097152 B
    float scale = (float)(log(135168.0) / log(1000.0) / 16.0);

    hipLaunchKernelGGL(k_prep, dim3(1120), dim3(256), 0, stream,
                       fc, fcT, Q, WTq, K, WTk, fm, V, vproj);
    hipLaunchKernelGGL(k_proj, dim3(64, 8), dim3(256), 0, stream,
                       WTq, WTk, fcT, qproj, kproj);
    hipLaunchKernelGGL(k_fused, dim3(256), dim3(1024), 0, stream,
                       qproj, kproj, kb, vproj, vb, fm, out, scale);
}